// Round 8
// baseline (293.523 us; speedup 1.0000x reference)
//
#include <hip/hip_runtime.h>

#define E 1024
#define HH 64
#define BB 4
#define SS 2048
#define BS (BB*SS)   // 8192 rows
#define NSLOT 144    // per-batch split-K slots: sum_{qt=0}^{31} (qt/4 + 1)

typedef unsigned short u16;
typedef short bf16x8 __attribute__((ext_vector_type(8)));
typedef float f32x4 __attribute__((ext_vector_type(4)));

#define LOG2E_O8 0.18033688011112042f   // log2(e)/8 : folds 1/sqrt(64) + exp2 domain

__device__ inline u16 f2bf(float f) {
    unsigned int u = __float_as_uint(f);
    unsigned int r = (u + 0x7FFFu + ((u >> 16) & 1u)) >> 16;   // RNE
    return (u16)r;
}

// ---------- Kernel 1: W' = W*gamma*scale (bf16), bias[h] = sum(beta*W[h])*scale ----------
// Folds LN's gamma/beta out of the GEMM (exact):  y_h = sum_e ((x-mu)*rstd)_e W'[h][e] + bias[h]
// Block 0 also zeroes the split-K tail counters (ws is poisoned 0xAA each launch).
__global__ __launch_bounds__(256) void w_cast(const float* __restrict__ Wq,
        const float* __restrict__ Wk, const float* __restrict__ Wv,
        const float* __restrict__ gamma, const float* __restrict__ beta,
        u16* __restrict__ wc, float* __restrict__ bias, int* __restrict__ cnt) {
    const int row = blockIdx.x;   // 0..191
    const int t = threadIdx.x;
    if (row == 0 && t < BB * 32) cnt[t] = 0;
    const float* src = (row < 64)  ? (Wq + (size_t)row * E)
                     : (row < 128) ? (Wk + (size_t)(row - 64) * E)
                                   : (Wv + (size_t)(row - 128) * E);
    const float sc = (row < 64) ? LOG2E_O8 : 1.0f;
    const float4 v = *(const float4*)(src + t * 4);
    const float4 g = *(const float4*)(gamma + t * 4);
    const float4 b = *(const float4*)(beta  + t * 4);
    ushort4 o;
    o.x = f2bf(v.x * g.x * sc); o.y = f2bf(v.y * g.y * sc);
    o.z = f2bf(v.z * g.z * sc); o.w = f2bf(v.w * g.w * sc);
    *(ushort4*)(wc + (size_t)row * E + t * 4) = o;

    float s = (v.x * b.x + v.y * b.y + v.z * b.z + v.w * b.w) * sc;
    #pragma unroll
    for (int off = 32; off > 0; off >>= 1) s += __shfl_xor(s, off);
    __shared__ float red[4];
    if ((t & 63) == 0) red[t >> 6] = s;
    __syncthreads();
    if (t == 0) bias[row] = red[0] + red[1] + red[2] + red[3];
}

// ---------- Kernel 2: fused LayerNorm + QKV projection (MFMA bf16) ----------
// Block = 32 rows x 96 cols (col half), 512 blocks. LN computed in-block; normalized
// X staged whole-K in 64 KB LDS using R3's zero-conflict slice pattern. Ws 12 KB
// single-buffered -> 78 KB LDS = 2 blocks/CU. xn round-trip eliminated.
__global__ __launch_bounds__(256) void lnqkv(const float* __restrict__ x,
        const u16* __restrict__ wc, const float* __restrict__ bias,
        u16* __restrict__ qb, u16* __restrict__ kb, u16* __restrict__ vt) {
    const int mb   = blockIdx.x >> 1;
    const int half = blockIdx.x & 1;
    const int row0 = mb * 32;
    const int t = threadIdx.x;
    const int w = t >> 6, lane = t & 63;
    const int quad = lane >> 4, r15 = lane & 15;
    const int mt = w >> 1, cgrp = w & 1;

    __shared__ u16 Xs[32 * 1024];   // 64 KB: X[row][16 slices][64k], chunk-swizzled per slice
    __shared__ u16 Ws[96 * 64];     // 12 KB
    __shared__ float smu[32], srs[32];

    // ---- LN stats: wave w -> rows w*8..w*8+7 (coalesced float4) ----
    #pragma unroll 2
    for (int i = 0; i < 8; ++i) {
        const int r = w * 8 + i;
        const float4* xr = (const float4*)(x + (size_t)(row0 + r) * E);
        float s = 0.f, sq = 0.f;
        #pragma unroll
        for (int jj = 0; jj < 4; ++jj) {
            const float4 v = xr[lane + 64 * jj];
            s  += v.x + v.y + v.z + v.w;
            sq += v.x*v.x + v.y*v.y + v.z*v.z + v.w*v.w;
        }
        #pragma unroll
        for (int off = 32; off > 0; off >>= 1) {
            s  += __shfl_xor(s,  off);
            sq += __shfl_xor(sq, off);
        }
        if (lane == 0) {
            const float mean = s * (1.0f / E);
            const float var  = sq * (1.0f / E) - mean * mean;
            smu[r] = mean;
            srs[r] = rsqrtf(var + 1e-5f);
        }
    }
    // staging row t>>3 belongs to wave t>>6 == (t>>3)>>3: same wave computed its stats,
    // so no barrier needed here (in-wave LDS ordering).

    // ---- stage X whole-K, normalized, R3 slice pattern (zero-conflict) ----
    {
        const int row = t >> 3, ch = t & 7;
        const float mu = smu[row], rs = srs[row];
        const float* xr = x + (size_t)(row0 + row) * E;   // L2-hot re-read
        const int phys = (ch ^ (row & 7)) * 8;
        #pragma unroll 4
        for (int s = 0; s < 16; ++s) {
            const float4 f0 = *(const float4*)(xr + s * 64 + ch * 8);
            const float4 f1 = *(const float4*)(xr + s * 64 + ch * 8 + 4);
            u16 tmp[8];
            tmp[0] = f2bf((f0.x - mu) * rs); tmp[1] = f2bf((f0.y - mu) * rs);
            tmp[2] = f2bf((f0.z - mu) * rs); tmp[3] = f2bf((f0.w - mu) * rs);
            tmp[4] = f2bf((f1.x - mu) * rs); tmp[5] = f2bf((f1.y - mu) * rs);
            tmp[6] = f2bf((f1.z - mu) * rs); tmp[7] = f2bf((f1.w - mu) * rs);
            *(uint4*)&Xs[row * 1024 + s * 64 + phys] = *(uint4*)tmp;
        }
    }

    // per-thread epilogue bias
    float bj[3];
    #pragma unroll
    for (int j = 0; j < 3; ++j) bj[j] = bias[half * 96 + cgrp * 48 + j * 16 + r15];

    f32x4 acc[3] = {};
    const int xrow = mt * 16 + r15;

    for (int kc = 0; kc < 16; ++kc) {
        __syncthreads();   // kc=0: Xs staged; kc>0: prior Ws reads done
        #pragma unroll
        for (int i = 0; i < 3; ++i) {   // stage W tile: 96 rows x 64 k
            const int idx = i * 256 + t;
            const int wl = idx >> 3, ch = idx & 7;
            const uint4 d = *(const uint4*)(wc + (size_t)(half * 96 + wl) * E + kc * 64 + ch * 8);
            *(uint4*)&Ws[wl * 64 + (ch ^ (wl & 7)) * 8] = d;
        }
        __syncthreads();
        #pragma unroll
        for (int kk = 0; kk < 2; ++kk) {
            const bf16x8 af = *(const bf16x8*)&Xs[xrow * 1024 + kc * 64
                                                 + ((kk * 4 + quad) ^ (xrow & 7)) * 8];
            #pragma unroll
            for (int j = 0; j < 3; ++j) {
                const int wl = (cgrp * 3 + j) * 16 + r15;
                const bf16x8 bfr = *(const bf16x8*)&Ws[wl * 64 + ((kk * 4 + quad) ^ (wl & 7)) * 8];
                acc[j] = __builtin_amdgcn_mfma_f32_16x16x32_bf16(af, bfr, acc[j], 0, 0, 0);
            }
        }
    }

    const int b    = row0 >> 11;
    const int key0 = row0 & 2047;
    #pragma unroll
    for (int j = 0; j < 3; ++j) {
        const int cg  = half * 96 + cgrp * 48 + j * 16 + r15;
        const int sel = cg >> 6;
        const int col = cg & 63;
        if (sel < 2) {
            u16* base = (sel == 0) ? qb : kb;
            #pragma unroll
            for (int r = 0; r < 4; ++r) {
                const size_t row = (size_t)row0 + mt * 16 + quad * 4 + r;
                base[row * HH + col] = f2bf(acc[j][r] + bj[j]);
            }
        } else {
            ushort4 pk;
            pk.x = f2bf(acc[j][0] + bj[j]); pk.y = f2bf(acc[j][1] + bj[j]);
            pk.z = f2bf(acc[j][2] + bj[j]); pk.w = f2bf(acc[j][3] + bj[j]);
            *(ushort4*)(vt + (size_t)b * HH * SS + (size_t)col * SS
                           + key0 + mt * 16 + quad * 4) = pk;
        }
    }
}

// ---------- Kernel 3: split-K causal flash attention + tail-block combine ----------
// Block = (b, qt: 64-query tile, c: 256-key chunk). Un-shifted exp2 softmax (bounded).
// nc==1 blocks write out directly; otherwise last-arriving block (atomic counter,
// device-scope fences) combines the partials in-kernel. No separate reduce dispatch.
__global__ __launch_bounds__(256) void attn_partial(const u16* __restrict__ qb,
        const u16* __restrict__ kb, const u16* __restrict__ vt,
        float* __restrict__ po, float* __restrict__ pl, int* __restrict__ cnt,
        float* __restrict__ out) {
    const int bid = blockIdx.x;
    const int b   = bid >> 8;
    const int rem = bid & 255;
    const int qt  = rem >> 3, c = rem & 7;
    const int a   = qt >> 2;
    if (c > a) return;                       // nc(qt) = a+1 chunks
    const int nc    = a + 1;
    const int r_    = qt & 3;
    const int sbase = b * NSLOT + 2 * a * (a + 1) + r_ * (a + 1);
    const int slot  = sbase + c;
    const int q0    = qt << 6;
    const int t = threadIdx.x;
    const int w = t >> 6, lane = t & 63;
    const int quad = lane >> 4, r15 = lane & 15;

    __shared__ u16 Ks[64 * 64];   // [key][h], XOR-swizzled chunks
    __shared__ u16 VT[64 * 64];   // [h][key], XOR-swizzled chunks
    __shared__ u16 Ps[64 * 64];   // [qrow][key], per-wave strips
    __shared__ int isLast;

    const size_t qrow = ((size_t)b * SS + q0 + w * 16 + r15) * HH;
    const bf16x8 qf0 = *(const bf16x8*)(qb + qrow + quad * 8);
    const bf16x8 qf1 = *(const bf16x8*)(qb + qrow + 32 + quad * 8);

    f32x4 o[4] = {};
    float l_[4] = {0.f, 0.f, 0.f, 0.f};

    const int t1 = min(c * 4 + 4, qt + 1);
    for (int tile = c * 4; tile < t1; ++tile) {
        const int kt = tile << 6;
        __syncthreads();
        {   // stage K tile [key][h]  (coalesced)
            const int row = t >> 2, ch0 = (t & 3) * 2;
            const uint4* src = (const uint4*)(kb + ((size_t)b * SS + kt + row) * HH + ch0 * 8);
            const uint4 d0 = src[0], d1 = src[1];
            *(uint4*)&Ks[row * 64 + ((ch0    ) ^ (row & 7)) * 8] = d0;
            *(uint4*)&Ks[row * 64 + ((ch0 + 1) ^ (row & 7)) * 8] = d1;
        }
        {   // stage V tile [h][key] from pre-transposed vt (coalesced)
            const int h = t >> 2, ch0 = (t & 3) * 2;
            const uint4* src = (const uint4*)(vt + (size_t)b * HH * SS + (size_t)h * SS + kt + ch0 * 8);
            const uint4 d0 = src[0], d1 = src[1];
            *(uint4*)&VT[h * 64 + ((ch0    ) ^ (h & 7)) * 8] = d0;
            *(uint4*)&VT[h * 64 + ((ch0 + 1) ^ (h & 7)) * 8] = d1;
        }
        __syncthreads();

        // S strip = Q K^T (16 x 64 per wave)
        f32x4 s[4] = {};
        #pragma unroll
        for (int nt = 0; nt < 4; ++nt) {
            const int krow = nt * 16 + r15;
            const bf16x8 k0 = *(const bf16x8*)&Ks[krow * 64 + ((    quad) ^ (krow & 7)) * 8];
            const bf16x8 k1 = *(const bf16x8*)&Ks[krow * 64 + ((4 + quad) ^ (krow & 7)) * 8];
            s[nt] = __builtin_amdgcn_mfma_f32_16x16x32_bf16(qf0, k0, s[nt], 0, 0, 0);
            s[nt] = __builtin_amdgcn_mfma_f32_16x16x32_bf16(qf1, k1, s[nt], 0, 0, 0);
        }
        if (tile == qt) {   // diagonal tile: mask key > query
            #pragma unroll
            for (int nt = 0; nt < 4; ++nt)
                #pragma unroll
                for (int r = 0; r < 4; ++r)
                    if (nt * 16 + r15 > w * 16 + quad * 4 + r) s[nt][r] = -INFINITY;
        }

        // un-shifted softmax accumulation: p = exp2(s) (bounded, cannot overflow)
        float p[4][4];
        #pragma unroll
        for (int r = 0; r < 4; ++r) {
            float rs = 0.f;
            #pragma unroll
            for (int nt = 0; nt < 4; ++nt) {
                p[nt][r] = __builtin_amdgcn_exp2f(s[nt][r]);
                rs += p[nt][r];
            }
            rs += __shfl_xor(rs, 1); rs += __shfl_xor(rs, 2);
            rs += __shfl_xor(rs, 4); rs += __shfl_xor(rs, 8);
            l_[r] += rs;
        }

        // P strip -> LDS (C-layout write), read back as A-frags (same wave only)
        #pragma unroll
        for (int nt = 0; nt < 4; ++nt)
            #pragma unroll
            for (int r = 0; r < 4; ++r) {
                const int prow = w * 16 + quad * 4 + r;
                const int col  = nt * 16 + r15;
                Ps[prow * 64 + (((col >> 3) ^ (prow & 7)) * 8) + (col & 7)] = f2bf(p[nt][r]);
            }
        const int arow = w * 16 + r15;
        const bf16x8 pf0 = *(const bf16x8*)&Ps[arow * 64 + ((    quad) ^ (arow & 7)) * 8];
        const bf16x8 pf1 = *(const bf16x8*)&Ps[arow * 64 + ((4 + quad) ^ (arow & 7)) * 8];

        // O strip += P V
        #pragma unroll
        for (int ht = 0; ht < 4; ++ht) {
            const int vrow = ht * 16 + r15;
            const bf16x8 v0 = *(const bf16x8*)&VT[vrow * 64 + ((    quad) ^ (vrow & 7)) * 8];
            const bf16x8 v1 = *(const bf16x8*)&VT[vrow * 64 + ((4 + quad) ^ (vrow & 7)) * 8];
            o[ht] = __builtin_amdgcn_mfma_f32_16x16x32_bf16(pf0, v0, o[ht], 0, 0, 0);
            o[ht] = __builtin_amdgcn_mfma_f32_16x16x32_bf16(pf1, v1, o[ht], 0, 0, 0);
        }
    }

    if (nc == 1) {   // qt<=3: this block saw all keys -> write out directly
        #pragma unroll
        for (int r = 0; r < 4; ++r) {
            const float inv = 1.0f / l_[r];
            const size_t orow = ((size_t)b * SS + q0 + w * 16 + quad * 4 + r) * HH;
            #pragma unroll
            for (int ht = 0; ht < 4; ++ht)
                out[orow + ht * 16 + r15] = o[ht][r] * inv;
        }
        return;
    }

    // write partials (raw o, l)
    #pragma unroll
    for (int r = 0; r < 4; ++r) {
        const int q = w * 16 + quad * 4 + r;
        #pragma unroll
        for (int ht = 0; ht < 4; ++ht)
            po[(size_t)slot * 4096 + q * 64 + ht * 16 + r15] = o[ht][r];
        if (r15 == 0) pl[slot * 64 + q] = l_[r];
    }

    // tail-block combine: last arriver merges all nc chunks (plain sums)
    __threadfence();                              // release: partials visible first
    if (t == 0) isLast = (atomicAdd(&cnt[b * 32 + qt], 1) == nc - 1);
    __syncthreads();
    if (!isLast) return;
    __threadfence();                              // acquire: see other blocks' partials

    const int h = t & 63;
    #pragma unroll 4
    for (int i = 0; i < 16; ++i) {
        const int q = (t >> 6) * 16 + i;
        float osum = 0.f, lsum = 0.f;
        for (int cidx = 0; cidx < nc; ++cidx) {
            osum += po[(size_t)(sbase + cidx) * 4096 + q * 64 + h];
            lsum += pl[(sbase + cidx) * 64 + q];
        }
        out[((size_t)b * SS + q0 + q) * HH + h] = osum / lsum;
    }
}

// ---------- launch ----------
extern "C" void kernel_launch(void* const* d_in, const int* in_sizes, int n_in,
                              void* d_out, int out_size, void* d_ws, size_t ws_size,
                              hipStream_t stream) {
    const float* x     = (const float*)d_in[0];
    const float* gamma = (const float*)d_in[1];
    const float* beta  = (const float*)d_in[2];
    const float* Wq    = (const float*)d_in[3];
    const float* Wk    = (const float*)d_in[4];
    const float* Wv    = (const float*)d_in[5];
    float* out = (float*)d_out;

    // ws layout: wc 384KB | bias 1KB | qb/kb/vt 1MB each | po 9.44MB | pl 144KB | cnt 512B
    char* p = (char*)d_ws;
    u16*   wc   = (u16*)p;                         p += 393216;
    float* bias = (float*)p;                       p += 1024;
    u16*   qb   = (u16*)p;                         p += (size_t)BS * HH * 2;
    u16*   kb   = (u16*)p;                         p += (size_t)BS * HH * 2;
    u16*   vt   = (u16*)p;                         p += (size_t)BS * HH * 2;
    float* po   = (float*)p;                       p += (size_t)BB * NSLOT * 4096 * 4;
    float* pl   = (float*)p;                       p += (size_t)BB * NSLOT * 64 * 4;
    int*   cnt  = (int*)p;

    w_cast      <<<192,         256, 0, stream>>>(Wq, Wk, Wv, gamma, beta, wc, bias, cnt);
    lnqkv       <<<BS / 16,     256, 0, stream>>>(x, wc, bias, qb, kb, vt);
    attn_partial<<<BB * 32 * 8, 256, 0, stream>>>(qb, kb, vt, po, pl, cnt, out);
}

// Round 9
// 132.851 us; speedup vs baseline: 2.2094x; 2.2094x over previous
//
#include <hip/hip_runtime.h>

#define E 1024
#define HH 64
#define BB 4
#define SS 2048
#define BS (BB*SS)   // 8192 rows
#define NSLOT 144    // per-batch split-K slots: sum_{qt=0}^{31} (qt/4 + 1)

typedef unsigned short u16;
typedef short bf16x8 __attribute__((ext_vector_type(8)));
typedef float f32x4 __attribute__((ext_vector_type(4)));

#define LOG2E_O8 0.18033688011112042f   // log2(e)/8 : folds 1/sqrt(64) + exp2 domain

__device__ inline u16 f2bf(float f) {
    unsigned int u = __float_as_uint(f);
    unsigned int r = (u + 0x7FFFu + ((u >> 16) & 1u)) >> 16;   // RNE
    return (u16)r;
}

// ---------- Kernel 1: W' = W*gamma*scale (bf16), bias[h] = sum(beta*W[h])*scale ----------
// Folds LN's gamma/beta out of the GEMM (exact): y_h = sum_e ((x-mu)*rstd)_e W'[h][e] + bias[h]
__global__ __launch_bounds__(256) void w_cast(const float* __restrict__ Wq,
        const float* __restrict__ Wk, const float* __restrict__ Wv,
        const float* __restrict__ gamma, const float* __restrict__ beta,
        u16* __restrict__ wc, float* __restrict__ bias) {
    const int row = blockIdx.x;   // 0..191
    const int t = threadIdx.x;
    const float* src = (row < 64)  ? (Wq + (size_t)row * E)
                     : (row < 128) ? (Wk + (size_t)(row - 64) * E)
                                   : (Wv + (size_t)(row - 128) * E);
    const float sc = (row < 64) ? LOG2E_O8 : 1.0f;
    const float4 v = *(const float4*)(src + t * 4);
    const float4 g = *(const float4*)(gamma + t * 4);
    const float4 b = *(const float4*)(beta  + t * 4);
    ushort4 o;
    o.x = f2bf(v.x * g.x * sc); o.y = f2bf(v.y * g.y * sc);
    o.z = f2bf(v.z * g.z * sc); o.w = f2bf(v.w * g.w * sc);
    *(ushort4*)(wc + (size_t)row * E + t * 4) = o;

    float s = (v.x * b.x + v.y * b.y + v.z * b.z + v.w * b.w) * sc;
    #pragma unroll
    for (int off = 32; off > 0; off >>= 1) s += __shfl_xor(s, off);
    __shared__ float red[4];
    if ((t & 63) == 0) red[t >> 6] = s;
    __syncthreads();
    if (t == 0) bias[row] = red[0] + red[1] + red[2] + red[3];
}

// ---------- Kernel 2: fused LayerNorm + QKV projection (MFMA bf16) ----------
// Block = 32 rows x 96 cols (col half), 512 blocks. LN computed in-block; normalized
// X staged whole-K in 64 KB LDS (zero-conflict slice pattern). Ws 12 KB single-buffered
// -> 78 KB LDS = 2 blocks/CU. xn HBM round-trip eliminated. [numerics verified R8]
__global__ __launch_bounds__(256) void lnqkv(const float* __restrict__ x,
        const u16* __restrict__ wc, const float* __restrict__ bias,
        u16* __restrict__ qb, u16* __restrict__ kb, u16* __restrict__ vt) {
    const int mb   = blockIdx.x >> 1;
    const int half = blockIdx.x & 1;
    const int row0 = mb * 32;
    const int t = threadIdx.x;
    const int w = t >> 6, lane = t & 63;
    const int quad = lane >> 4, r15 = lane & 15;
    const int mt = w >> 1, cgrp = w & 1;

    __shared__ u16 Xs[32 * 1024];   // 64 KB: X[row][16 slices][64k], chunk-swizzled per slice
    __shared__ u16 Ws[96 * 64];     // 12 KB
    __shared__ float smu[32], srs[32];

    // ---- LN stats: wave w -> rows w*8..w*8+7 (coalesced float4) ----
    #pragma unroll 2
    for (int i = 0; i < 8; ++i) {
        const int r = w * 8 + i;
        const float4* xr = (const float4*)(x + (size_t)(row0 + r) * E);
        float s = 0.f, sq = 0.f;
        #pragma unroll
        for (int jj = 0; jj < 4; ++jj) {
            const float4 v = xr[lane + 64 * jj];
            s  += v.x + v.y + v.z + v.w;
            sq += v.x*v.x + v.y*v.y + v.z*v.z + v.w*v.w;
        }
        #pragma unroll
        for (int off = 32; off > 0; off >>= 1) {
            s  += __shfl_xor(s,  off);
            sq += __shfl_xor(sq, off);
        }
        if (lane == 0) {
            const float mean = s * (1.0f / E);
            const float var  = sq * (1.0f / E) - mean * mean;
            smu[r] = mean;
            srs[r] = rsqrtf(var + 1e-5f);
        }
    }
    // staging row t>>3 belongs to wave (t>>3)>>3 == t>>6: same wave computed its stats
    // -> in-wave LDS ordering suffices, no barrier.

    // ---- stage X whole-K, normalized (zero-conflict slice pattern) ----
    {
        const int row = t >> 3, ch = t & 7;
        const float mu = smu[row], rs = srs[row];
        const float* xr = x + (size_t)(row0 + row) * E;   // L2/L3-hot re-read
        const int phys = (ch ^ (row & 7)) * 8;
        #pragma unroll 4
        for (int s = 0; s < 16; ++s) {
            const float4 f0 = *(const float4*)(xr + s * 64 + ch * 8);
            const float4 f1 = *(const float4*)(xr + s * 64 + ch * 8 + 4);
            u16 tmp[8];
            tmp[0] = f2bf((f0.x - mu) * rs); tmp[1] = f2bf((f0.y - mu) * rs);
            tmp[2] = f2bf((f0.z - mu) * rs); tmp[3] = f2bf((f0.w - mu) * rs);
            tmp[4] = f2bf((f1.x - mu) * rs); tmp[5] = f2bf((f1.y - mu) * rs);
            tmp[6] = f2bf((f1.z - mu) * rs); tmp[7] = f2bf((f1.w - mu) * rs);
            *(uint4*)&Xs[row * 1024 + s * 64 + phys] = *(uint4*)tmp;
        }
    }

    // per-thread epilogue bias
    float bj[3];
    #pragma unroll
    for (int j = 0; j < 3; ++j) bj[j] = bias[half * 96 + cgrp * 48 + j * 16 + r15];

    f32x4 acc[3] = {};
    const int xrow = mt * 16 + r15;

    for (int kc = 0; kc < 16; ++kc) {
        __syncthreads();   // kc=0: Xs staged; kc>0: prior Ws reads done
        #pragma unroll
        for (int i = 0; i < 3; ++i) {   // stage W tile: 96 rows x 64 k
            const int idx = i * 256 + t;
            const int wl = idx >> 3, ch = idx & 7;
            const uint4 d = *(const uint4*)(wc + (size_t)(half * 96 + wl) * E + kc * 64 + ch * 8);
            *(uint4*)&Ws[wl * 64 + (ch ^ (wl & 7)) * 8] = d;
        }
        __syncthreads();
        #pragma unroll
        for (int kk = 0; kk < 2; ++kk) {
            const bf16x8 af = *(const bf16x8*)&Xs[xrow * 1024 + kc * 64
                                                 + ((kk * 4 + quad) ^ (xrow & 7)) * 8];
            #pragma unroll
            for (int j = 0; j < 3; ++j) {
                const int wl = (cgrp * 3 + j) * 16 + r15;
                const bf16x8 bfr = *(const bf16x8*)&Ws[wl * 64 + ((kk * 4 + quad) ^ (wl & 7)) * 8];
                acc[j] = __builtin_amdgcn_mfma_f32_16x16x32_bf16(af, bfr, acc[j], 0, 0, 0);
            }
        }
    }

    const int b    = row0 >> 11;
    const int key0 = row0 & 2047;
    #pragma unroll
    for (int j = 0; j < 3; ++j) {
        const int cg  = half * 96 + cgrp * 48 + j * 16 + r15;
        const int sel = cg >> 6;
        const int col = cg & 63;
        if (sel < 2) {
            u16* base = (sel == 0) ? qb : kb;
            #pragma unroll
            for (int r = 0; r < 4; ++r) {
                const size_t row = (size_t)row0 + mt * 16 + quad * 4 + r;
                base[row * HH + col] = f2bf(acc[j][r] + bj[j]);
            }
        } else {
            ushort4 pk;
            pk.x = f2bf(acc[j][0] + bj[j]); pk.y = f2bf(acc[j][1] + bj[j]);
            pk.z = f2bf(acc[j][2] + bj[j]); pk.w = f2bf(acc[j][3] + bj[j]);
            *(ushort4*)(vt + (size_t)b * HH * SS + (size_t)col * SS
                           + key0 + mt * 16 + quad * 4) = pk;
        }
    }
}

// ---------- Kernel 3: split-K causal flash attention (partials), 256-key chunks ----------
// R7-proven: un-shifted exp2 softmax, raw (o,l) partials, NO in-kernel combine
// (cross-XCD fences cost ~100 us — R8). Blocks with nc==1 (qt<=3) write out directly.
__global__ __launch_bounds__(256) void attn_partial(const u16* __restrict__ qb,
        const u16* __restrict__ kb, const u16* __restrict__ vt,
        float* __restrict__ po, float* __restrict__ pl,
        float* __restrict__ out) {
    const int bid = blockIdx.x;
    const int b   = bid >> 8;
    const int rem = bid & 255;
    const int qt  = rem >> 3, c = rem & 7;
    const int a   = qt >> 2;
    if (c > a) return;                       // nc(qt) = a+1 chunks
    const int nc   = a + 1;
    const int r_   = qt & 3;
    const int slot = b * NSLOT + 2 * a * (a + 1) + r_ * (a + 1) + c;
    const int q0   = qt << 6;
    const int t = threadIdx.x;
    const int w = t >> 6, lane = t & 63;
    const int quad = lane >> 4, r15 = lane & 15;

    __shared__ u16 Ks[64 * 64];   // [key][h], XOR-swizzled chunks
    __shared__ u16 VT[64 * 64];   // [h][key], XOR-swizzled chunks
    __shared__ u16 Ps[64 * 64];   // [qrow][key], per-wave strips

    const size_t qrow = ((size_t)b * SS + q0 + w * 16 + r15) * HH;
    const bf16x8 qf0 = *(const bf16x8*)(qb + qrow + quad * 8);
    const bf16x8 qf1 = *(const bf16x8*)(qb + qrow + 32 + quad * 8);

    f32x4 o[4] = {};
    float l_[4] = {0.f, 0.f, 0.f, 0.f};

    const int t1 = min(c * 4 + 4, qt + 1);
    for (int tile = c * 4; tile < t1; ++tile) {
        const int kt = tile << 6;
        __syncthreads();
        {   // stage K tile [key][h]  (coalesced)
            const int row = t >> 2, ch0 = (t & 3) * 2;
            const uint4* src = (const uint4*)(kb + ((size_t)b * SS + kt + row) * HH + ch0 * 8);
            const uint4 d0 = src[0], d1 = src[1];
            *(uint4*)&Ks[row * 64 + ((ch0    ) ^ (row & 7)) * 8] = d0;
            *(uint4*)&Ks[row * 64 + ((ch0 + 1) ^ (row & 7)) * 8] = d1;
        }
        {   // stage V tile [h][key] from pre-transposed vt (coalesced)
            const int h = t >> 2, ch0 = (t & 3) * 2;
            const uint4* src = (const uint4*)(vt + (size_t)b * HH * SS + (size_t)h * SS + kt + ch0 * 8);
            const uint4 d0 = src[0], d1 = src[1];
            *(uint4*)&VT[h * 64 + ((ch0    ) ^ (h & 7)) * 8] = d0;
            *(uint4*)&VT[h * 64 + ((ch0 + 1) ^ (h & 7)) * 8] = d1;
        }
        __syncthreads();

        // S strip = Q K^T (16 x 64 per wave)
        f32x4 s[4] = {};
        #pragma unroll
        for (int nt = 0; nt < 4; ++nt) {
            const int krow = nt * 16 + r15;
            const bf16x8 k0 = *(const bf16x8*)&Ks[krow * 64 + ((    quad) ^ (krow & 7)) * 8];
            const bf16x8 k1 = *(const bf16x8*)&Ks[krow * 64 + ((4 + quad) ^ (krow & 7)) * 8];
            s[nt] = __builtin_amdgcn_mfma_f32_16x16x32_bf16(qf0, k0, s[nt], 0, 0, 0);
            s[nt] = __builtin_amdgcn_mfma_f32_16x16x32_bf16(qf1, k1, s[nt], 0, 0, 0);
        }
        if (tile == qt) {   // diagonal tile: mask key > query
            #pragma unroll
            for (int nt = 0; nt < 4; ++nt)
                #pragma unroll
                for (int r = 0; r < 4; ++r)
                    if (nt * 16 + r15 > w * 16 + quad * 4 + r) s[nt][r] = -INFINITY;
        }

        // un-shifted softmax accumulation: p = exp2(s) (bounded, cannot overflow)
        float p[4][4];
        #pragma unroll
        for (int r = 0; r < 4; ++r) {
            float rs = 0.f;
            #pragma unroll
            for (int nt = 0; nt < 4; ++nt) {
                p[nt][r] = __builtin_amdgcn_exp2f(s[nt][r]);
                rs += p[nt][r];
            }
            rs += __shfl_xor(rs, 1); rs += __shfl_xor(rs, 2);
            rs += __shfl_xor(rs, 4); rs += __shfl_xor(rs, 8);
            l_[r] += rs;
        }

        // P strip -> LDS (C-layout write), read back as A-frags (same wave only)
        #pragma unroll
        for (int nt = 0; nt < 4; ++nt)
            #pragma unroll
            for (int r = 0; r < 4; ++r) {
                const int prow = w * 16 + quad * 4 + r;
                const int col  = nt * 16 + r15;
                Ps[prow * 64 + (((col >> 3) ^ (prow & 7)) * 8) + (col & 7)] = f2bf(p[nt][r]);
            }
        const int arow = w * 16 + r15;
        const bf16x8 pf0 = *(const bf16x8*)&Ps[arow * 64 + ((    quad) ^ (arow & 7)) * 8];
        const bf16x8 pf1 = *(const bf16x8*)&Ps[arow * 64 + ((4 + quad) ^ (arow & 7)) * 8];

        // O strip += P V
        #pragma unroll
        for (int ht = 0; ht < 4; ++ht) {
            const int vrow = ht * 16 + r15;
            const bf16x8 v0 = *(const bf16x8*)&VT[vrow * 64 + ((    quad) ^ (vrow & 7)) * 8];
            const bf16x8 v1 = *(const bf16x8*)&VT[vrow * 64 + ((4 + quad) ^ (vrow & 7)) * 8];
            o[ht] = __builtin_amdgcn_mfma_f32_16x16x32_bf16(pf0, v0, o[ht], 0, 0, 0);
            o[ht] = __builtin_amdgcn_mfma_f32_16x16x32_bf16(pf1, v1, o[ht], 0, 0, 0);
        }
    }

    if (nc == 1) {   // qt<=3: this block saw all keys -> write out directly
        #pragma unroll
        for (int r = 0; r < 4; ++r) {
            const float inv = 1.0f / l_[r];
            const size_t orow = ((size_t)b * SS + q0 + w * 16 + quad * 4 + r) * HH;
            #pragma unroll
            for (int ht = 0; ht < 4; ++ht)
                out[orow + ht * 16 + r15] = o[ht][r] * inv;
        }
        return;
    }
    #pragma unroll
    for (int r = 0; r < 4; ++r) {
        const int q = w * 16 + quad * 4 + r;
        #pragma unroll
        for (int ht = 0; ht < 4; ++ht)
            po[(size_t)slot * 4096 + q * 64 + ht * 16 + r15] = o[ht][r];
        if (r15 == 0) pl[slot * 64 + q] = l_[r];
    }
}

// ---------- Kernel 4: split-K reduce — plain sums (no max merge) ----------
__global__ __launch_bounds__(256) void attn_reduce(const float* __restrict__ po,
        const float* __restrict__ pl, float* __restrict__ out) {
    const int bid = blockIdx.x;            // BB*32*4
    const int b = bid >> 7, rem = bid & 127;
    const int qt = rem >> 2, qq = rem & 3;
    if (qt < 4) return;                    // qt<=3 written directly
    const int a = qt >> 2, r_ = qt & 3;
    const int nc = a + 1;
    const int sbase = b * NSLOT + 2 * a * (a + 1) + r_ * (a + 1);
    const int t = threadIdx.x;
    const int h = t & 63, qr = t >> 6;
    #pragma unroll
    for (int i = 0; i < 4; ++i) {
        const int q = qq * 16 + qr * 4 + i;   // query within 64-tile
        float osum = 0.f, lsum = 0.f;
        for (int cidx = 0; cidx < nc; ++cidx) {
            osum += po[(size_t)(sbase + cidx) * 4096 + q * 64 + h];
            lsum += pl[(sbase + cidx) * 64 + q];
        }
        out[((size_t)b * SS + (qt << 6) + q) * HH + h] = osum / lsum;
    }
}

// ---------- launch ----------
extern "C" void kernel_launch(void* const* d_in, const int* in_sizes, int n_in,
                              void* d_out, int out_size, void* d_ws, size_t ws_size,
                              hipStream_t stream) {
    const float* x     = (const float*)d_in[0];
    const float* gamma = (const float*)d_in[1];
    const float* beta  = (const float*)d_in[2];
    const float* Wq    = (const float*)d_in[3];
    const float* Wk    = (const float*)d_in[4];
    const float* Wv    = (const float*)d_in[5];
    float* out = (float*)d_out;

    // ws layout: wc 384KB | bias 1KB | qb/kb/vt 1MB each | po 9.44MB | pl 144KB
    char* p = (char*)d_ws;
    u16*   wc   = (u16*)p;                         p += 393216;
    float* bias = (float*)p;                       p += 1024;
    u16*   qb   = (u16*)p;                         p += (size_t)BS * HH * 2;
    u16*   kb   = (u16*)p;                         p += (size_t)BS * HH * 2;
    u16*   vt   = (u16*)p;                         p += (size_t)BS * HH * 2;
    float* po   = (float*)p;                       p += (size_t)BB * NSLOT * 4096 * 4;
    float* pl   = (float*)p;

    w_cast      <<<192,         256, 0, stream>>>(Wq, Wk, Wv, gamma, beta, wc, bias);
    lnqkv       <<<BS / 16,     256, 0, stream>>>(x, wc, bias, qb, kb, vt);
    attn_partial<<<BB * 32 * 8, 256, 0, stream>>>(qb, kb, vt, po, pl, out);
    attn_reduce <<<BB * 32 * 4, 256, 0, stream>>>(po, pl, out);
}